// Round 3
// baseline (4782.483 us; speedup 1.0000x reference)
//
#include <hip/hip_runtime.h>
#include <cstdint>
#include <cstddef>

#define T_SEQ 1024
#define BATCH 64
#define DIM   256
#define HID   256
#define NG    (4*HID)   // 1024 gate columns, j' = r*4 + g, g in {f,i,g~,o}

typedef _Float16 half8 __attribute__((ext_vector_type(8)));
typedef float f32x4 __attribute__((ext_vector_type(4)));
union U16H { uint4 u; half8 h; };

__device__ __forceinline__ float sigm_f(float x) {
    return 1.0f / (1.0f + __expf(-x));
}
__device__ __forceinline__ float tanh_f(float x) {
    x = fminf(fmaxf(x, -15.0f), 15.0f);   // avoid inf/inf
    float e = __expf(2.0f * x);
    return (e - 1.0f) / (e + 1.0f);
}

// quad_perm DPP broadcast/permute (VALU pipe — keeps epilogue off the LDS pipe)
#define QPERM(x, c) __int_as_float(__builtin_amdgcn_mov_dpp(__float_as_int(x), (c), 0xf, 0xf, true))

// ---------------- phase 0: repack weights, zero state -------------------------
// wx4[k*1024 + j'] = W_g[r][k]        (x part, fp32; j' = r*4+g)
// whB: h-part weights in MFMA B-fragment order (fp16):
//   element (k, j'): kt=k>>5, q=(k>>3)&3, s=k&7, T=j'>>4, lane=q*16+(j'&15)
//   whB[((kt*64 + T)*64 + lane)*8 + s] = fp16(W_g[r][256+k])
// bias4[j'] = b_g[r]
__global__ void pack_kernel(const float* __restrict__ Wf, const float* __restrict__ bf,
                            const float* __restrict__ Wi, const float* __restrict__ bi,
                            const float* __restrict__ Wg, const float* __restrict__ bg,
                            const float* __restrict__ Wo, const float* __restrict__ bo,
                            float* __restrict__ wx4, _Float16* __restrict__ whB,
                            float* __restrict__ bias4,
                            float* __restrict__ hstate, float* __restrict__ cstate) {
    int k = blockIdx.x;          // 0..255
    int j = threadIdx.x;         // 0..1023
    int r = j & 255, g = j >> 8;
    const float* W  = (g == 0) ? Wf : (g == 1) ? Wi : (g == 2) ? Wg : Wo;
    const float* bb = (g == 0) ? bf : (g == 1) ? bi : (g == 2) ? bg : bo;
    int jp = r * 4 + g;          // j' gate-interleaved column index
    wx4[(size_t)k * 1024 + jp] = W[(size_t)r * 512 + k];
    {
        int kt = k >> 5, q = (k >> 3) & 3, s = k & 7;
        int T = jp >> 4, lane = q * 16 + (jp & 15);
        whB[(((size_t)kt * 64 + T) * 64 + lane) * 8 + s] = (_Float16)W[(size_t)r * 512 + 256 + k];
    }
    if (k == 0) bias4[jp] = bb[r];
    if (k < 64 && g == 0) hstate[k * 256 + r] = 0.0f;
    if (k < 64 && g == 1) cstate[k * 256 + r] = 0.0f;
}

// ---------------- phase 1: Xproj ----------------------------------------------
// xp[row][j'] with j' = tid*4+g contiguous -> float4 stores, and the recurrence
// reads 16 coalesced scalars per lane.
__global__ __launch_bounds__(256) void xproj_kernel(
        const float* __restrict__ X, const float* __restrict__ wx4,
        const float* __restrict__ bias4, float4* __restrict__ xp) {
    __shared__ __align__(16) float xl[256 * 20];   // [k][row] padded
    int tid = threadIdx.x;
    int R0 = blockIdx.x * 16;
    #pragma unroll
    for (int i = 0; i < 16; ++i)
        xl[tid * 20 + i] = X[(size_t)(R0 + i) * DIM + tid];
    __syncthreads();

    float4 bv = ((const float4*)bias4)[tid];
    float acc[16][4];
    #pragma unroll
    for (int i = 0; i < 16; ++i) {
        acc[i][0] = bv.x; acc[i][1] = bv.y; acc[i][2] = bv.z; acc[i][3] = bv.w;
    }
    const float4* __restrict__ wp = (const float4*)wx4 + tid;
    #pragma unroll 2
    for (int k = 0; k < 256; ++k) {
        float4 w  = wp[k << 8];
        float4 xa = *(const float4*)&xl[k * 20 + 0];
        float4 xb = *(const float4*)&xl[k * 20 + 4];
        float4 xc = *(const float4*)&xl[k * 20 + 8];
        float4 xd = *(const float4*)&xl[k * 20 + 12];
        float xr[16] = {xa.x, xa.y, xa.z, xa.w, xb.x, xb.y, xb.z, xb.w,
                        xc.x, xc.y, xc.z, xc.w, xd.x, xd.y, xd.z, xd.w};
        #pragma unroll
        for (int i = 0; i < 16; ++i) {
            acc[i][0] = fmaf(xr[i], w.x, acc[i][0]);
            acc[i][1] = fmaf(xr[i], w.y, acc[i][1]);
            acc[i][2] = fmaf(xr[i], w.z, acc[i][2]);
            acc[i][3] = fmaf(xr[i], w.w, acc[i][3]);
        }
    }
    #pragma unroll
    for (int i = 0; i < 16; ++i) {
        float4 v;
        v.x = acc[i][0]; v.y = acc[i][1]; v.z = acc[i][2]; v.w = acc[i][3];
        xp[(size_t)(R0 + i) * 256 + tid] = v;   // row*1024 + tid*4 .. +3 (j' order)
    }
}

// ---------------- phase 2: MFMA recurrence, 1 WG (4 waves) per batch ---------
// gates[1024] = h[256] @ Wh[256][1024] via mfma_f32_16x16x32_f16 with M=16
// (rows duplicated: every lane's A-frag = same h slice -> all D rows equal,
// so only the HW-verified D col=lane&15 mapping matters).
// Wave w owns j'-tiles T = w*16 .. w*16+15 (128 r-rows per... 64 r per wave).
// Weights: kt 0,1 in LDS (128KB); kt 3..7 in 320 VGPRs/lane; kt 2 streamed
// from L2 each step. One __syncthreads per step; h double-buffered in LDS;
// c in registers (quad-redundant); gate exchange via quad_perm DPP (VALU).
__global__ __launch_bounds__(256, 1) void lstm_step_kernel(
        const float* __restrict__ xp, const _Float16* __restrict__ whB,
        float* __restrict__ hstate, float* __restrict__ cstate,
        float* __restrict__ out, int t0, int Tc) {
    __shared__ __align__(16) _Float16 blds[2 * 64 * 64 * 8];   // 128 KB: kt = 0,1
    __shared__ __align__(16) _Float16 hl[2][HID];              // double-buffered h
    int tid = threadIdx.x, b = blockIdx.x;
    int l = tid & 63, w = tid >> 6;

    // stage kt=0,1 (8192 uint4 over 256 threads)
    {
        const uint4* src = (const uint4*)whB;
        uint4* dst = (uint4*)blds;
        #pragma unroll
        for (int i = 0; i < 32; ++i)
            dst[i * 256 + tid] = src[i * 256 + tid];
    }
    // register slab: kt = 3..7, 16 tiles each (80 uint4 = 320 VGPRs)
    U16H wreg[5][16];
    {
        const uint4* src = (const uint4*)whB;
        #pragma unroll
        for (int kt = 0; kt < 5; ++kt)
            #pragma unroll
            for (int n = 0; n < 16; ++n)
                wreg[kt][n].u = src[(size_t)((kt + 3) * 64 + w * 16 + n) * 64 + l];
    }
    // state: c per quad (redundant across the 4 gate-lanes and the 4 row-copies)
    float c_reg[16];
    int rsub = (l & 15) >> 2;
    #pragma unroll
    for (int n = 0; n < 16; ++n)
        c_reg[n] = cstate[b * HID + (w * 16 + n) * 4 + rsub];
    if (tid < HID) hl[0][tid] = (_Float16)hstate[b * HID + tid];

    int g = l & 3;
    float sm = (g == 2) ? 2.0f : 1.0f;            // tanh(x) = 2*sigm(2x)-1
    float aa = sm, bbc = (g == 2) ? -1.0f : 0.0f;
    bool wmask = (l < 16) && ((l & 3) == 0);
    bool pl0 = (l < 16);

    __syncthreads();

    float xa[16], xan[16];
    {
        const float* xr = xp + (size_t)b * NG;
        #pragma unroll
        for (int n = 0; n < 16; ++n)
            xa[n] = xr[w * 256 + n * 16 + (l & 15)];
    }
    int cur = 0;
    for (int tt = 0; tt < Tc; ++tt) {
        // prefetch next step's xp (hidden under this step's MFMA phase)
        {
            int tn = (tt + 1 < Tc) ? tt + 1 : tt;
            const float* xr = xp + (size_t)(tn * BATCH + b) * NG;
            #pragma unroll
            for (int n = 0; n < 16; ++n)
                xan[n] = xr[w * 256 + n * 16 + (l & 15)];
        }
        const _Float16* hb = hl[cur];
        #pragma unroll
        for (int h2 = 0; h2 < 2; ++h2) {
            // stream kt=2 b-frags from L2 (issued first, consumed last)
            U16H g2[8];
            #pragma unroll
            for (int nn = 0; nn < 8; ++nn)
                g2[nn].u = ((const uint4*)whB)[(size_t)(2 * 64 + w * 16 + h2 * 8 + nn) * 64 + l];
            f32x4 acc[8];
            #pragma unroll
            for (int nn = 0; nn < 8; ++nn) {
                f32x4 a;
                a[0] = pl0 ? xa[h2 * 8 + nn] : 0.0f;
                a[1] = 0.0f; a[2] = 0.0f; a[3] = 0.0f;
                acc[nn] = a;
            }
            // kt 3..7 from registers
            #pragma unroll
            for (int kt = 0; kt < 5; ++kt) {
                U16H af; af.u = *(const uint4*)&hb[(kt + 3) * 32 + (l >> 4) * 8];
                #pragma unroll
                for (int nn = 0; nn < 8; ++nn)
                    acc[nn] = __builtin_amdgcn_mfma_f32_16x16x32_f16(
                        af.h, wreg[kt][h2 * 8 + nn].h, acc[nn], 0, 0, 0);
            }
            // kt 0,1 from LDS
            #pragma unroll
            for (int kt = 0; kt < 2; ++kt) {
                U16H af; af.u = *(const uint4*)&hb[kt * 32 + (l >> 4) * 8];
                #pragma unroll
                for (int nn = 0; nn < 8; ++nn) {
                    U16H bf;
                    bf.u = *((const uint4*)blds + (size_t)(kt * 64 + w * 16 + h2 * 8 + nn) * 64 + l);
                    acc[nn] = __builtin_amdgcn_mfma_f32_16x16x32_f16(
                        af.h, bf.h, acc[nn], 0, 0, 0);
                }
            }
            // kt 2 (streamed)
            {
                U16H af; af.u = *(const uint4*)&hb[2 * 32 + (l >> 4) * 8];
                #pragma unroll
                for (int nn = 0; nn < 8; ++nn)
                    acc[nn] = __builtin_amdgcn_mfma_f32_16x16x32_f16(
                        af.h, g2[nn].h, acc[nn], 0, 0, 0);
            }
            // epilogue: lane quad holds (f,i,g~,o) of one r for this tile
            #pragma unroll
            for (int nn = 0; nn < 8; ++nn) {
                int n = h2 * 8 + nn;
                float y   = acc[nn][0];
                float s   = sigm_f(sm * y);
                float val = fmaf(aa, s, bbc);       // f/i/o: sigm, g~: tanh
                float t3  = QPERM(val, 0x1B);       // xor-3 within quad
                float m1  = val * t3;               // lanes 1,2: i*g~
                float ig  = QPERM(m1, 0x55);        // all <- lane1: i*g~
                float ff  = QPERM(val, 0x00);       // all <- lane0: f
                float oo  = QPERM(val, 0xFF);       // all <- lane3: o
                float c   = fmaf(ff, c_reg[n], ig);
                c_reg[n]  = c;
                float h   = oo * tanh_f(c);
                if (wmask) {
                    int r = (w * 16 + n) * 4 + (l >> 2);
                    hl[cur ^ 1][r] = (_Float16)h;
                }
            }
        }
        __syncthreads();
        // coalesced out store from LDS, post-barrier (ack drains at next barrier)
        out[((size_t)(t0 + tt) * BATCH + b) * HID + tid] = (float)hl[cur ^ 1][tid];
        #pragma unroll
        for (int n = 0; n < 16; ++n) xa[n] = xan[n];
        cur ^= 1;
    }
    if (tid < HID) hstate[b * HID + tid] = (float)hl[cur][tid];
    if (wmask) {
        #pragma unroll
        for (int n = 0; n < 16; ++n)
            cstate[b * HID + (w * 16 + n) * 4 + (l >> 2)] = c_reg[n];
    }
}

// ---------------- tail: final hx, cx ------------------------------------------
__global__ void tail_kernel(const float* __restrict__ hstate,
                            const float* __restrict__ cstate, float* __restrict__ out) {
    int b = blockIdx.x, r = threadIdx.x;
    size_t base = (size_t)T_SEQ * BATCH * HID;
    out[base + b * HID + r] = hstate[b * HID + r];
    out[base + (size_t)BATCH * HID + b * HID + r] = cstate[b * HID + r];
}

extern "C" void kernel_launch(void* const* d_in, const int* in_sizes, int n_in,
                              void* d_out, int out_size, void* d_ws, size_t ws_size,
                              hipStream_t stream) {
    (void)in_sizes; (void)n_in; (void)out_size;
    const float* X  = (const float*)d_in[0];
    const float* Wf = (const float*)d_in[1];
    const float* bf = (const float*)d_in[2];
    const float* Wi = (const float*)d_in[3];
    const float* bi = (const float*)d_in[4];
    const float* Wg = (const float*)d_in[5];
    const float* bg = (const float*)d_in[6];
    const float* Wo = (const float*)d_in[7];
    const float* bo = (const float*)d_in[8];
    float* out = (float*)d_out;
    char*  ws  = (char*)d_ws;

    const size_t MB = 1 << 20, KB = 1 << 10;
    float*    wx4    = (float*)(ws);                          // 1 MB
    _Float16* whB    = (_Float16*)(ws + MB);                  // 512 KB
    float*    bias4  = (float*)(ws + MB + 512 * KB);          // 4 KB
    float*    hstate = (float*)(ws + MB + 576 * KB);          // 64 KB
    float*    cstate = (float*)(ws + MB + 640 * KB);          // 64 KB
    float4*   xproj  = (float4*)(ws + 2 * MB);

    size_t fixed = 2 * MB;
    int Tc = 1024;
    while (Tc > 16 && fixed + (size_t)Tc * BATCH * NG * 4 > ws_size) Tc >>= 1;

    pack_kernel<<<256, 1024, 0, stream>>>(Wf, bf, Wi, bi, Wg, bg, Wo, bo,
                                          wx4, whB, bias4, hstate, cstate);
    for (int t0 = 0; t0 < T_SEQ; t0 += Tc) {
        xproj_kernel<<<Tc * BATCH / 16, 256, 0, stream>>>(
            X + (size_t)t0 * BATCH * DIM, wx4, bias4, xproj);
        lstm_step_kernel<<<BATCH, 256, 0, stream>>>(
            (const float*)xproj, whB, hstate, cstate, out, t0, Tc);
    }
    tail_kernel<<<BATCH, HID, 0, stream>>>(hstate, cstate, out);
}

// Round 4
// 2057.533 us; speedup vs baseline: 2.3244x; 2.3244x over previous
//
#include <hip/hip_runtime.h>
#include <cstdint>
#include <cstddef>

#define T_SEQ 1024
#define BATCH 64
#define DIM   256
#define HID   256
#define NG    (4*HID)   // 1024 gate columns, j' = 4r + g, g in {f,i,g~,o}

typedef _Float16 h2v __attribute__((ext_vector_type(2)));
union U16 { uint4 u; h2v h[4]; };

__device__ __forceinline__ float sigm_f(float x) {
    return 1.0f / (1.0f + __expf(-x));
}
__device__ __forceinline__ float tanh_f(float x) {
    x = fminf(fmaxf(x, -15.0f), 15.0f);   // avoid inf/inf
    float e = __expf(2.0f * x);
    return (e - 1.0f) / (e + 1.0f);
}

// DPP quad_perm [1,0,3,2] = swap adjacent lane pairs (xor-1), VALU pipe
#define QP_XOR1(x) __int_as_float(__builtin_amdgcn_mov_dpp(__float_as_int(x), 0xB1, 0xf, 0xf, true))

// ---------------- phase 0: repack weights, zero state -------------------------
// wx4[k*1024 + jp] = W_g[r][k]            (x part, fp32; jp = 4r+g)
// whB (h part, fp16, k-packs of 8), column-pair layout for the recurrence:
//   col jp -> thread t = jp>>1, slot s = jp&1; chunk k8 = k>>3, elem e = k&7
//   whB[((k8*2 + s)*512 + t)*8 + e] = fp16(W_g[r][256+k])
// bias4[jp] = b_g[r]
__global__ void pack_kernel(const float* __restrict__ Wf, const float* __restrict__ bf,
                            const float* __restrict__ Wi, const float* __restrict__ bi,
                            const float* __restrict__ Wg, const float* __restrict__ bg,
                            const float* __restrict__ Wo, const float* __restrict__ bo,
                            float* __restrict__ wx4, _Float16* __restrict__ whB,
                            float* __restrict__ bias4,
                            float* __restrict__ hstate, float* __restrict__ cstate) {
    int k = blockIdx.x;          // 0..255
    int j = threadIdx.x;         // 0..1023
    int r = j & 255, g = j >> 8;
    const float* W  = (g == 0) ? Wf : (g == 1) ? Wi : (g == 2) ? Wg : Wo;
    const float* bb = (g == 0) ? bf : (g == 1) ? bi : (g == 2) ? bg : bo;
    int jp = r * 4 + g;
    wx4[(size_t)k * 1024 + jp] = W[(size_t)r * 512 + k];
    {
        int k8 = k >> 3, e = k & 7, t = jp >> 1, s = jp & 1;
        whB[(((size_t)(k8 * 2 + s)) * 512 + t) * 8 + e] = (_Float16)W[(size_t)r * 512 + 256 + k];
    }
    if (k == 0) bias4[jp] = bb[r];
    if (k < 64 && g == 0) hstate[k * 256 + r] = 0.0f;
    if (k < 64 && g == 1) cstate[k * 256 + r] = 0.0f;
}

// ---------------- phase 1: Xproj ----------------------------------------------
// xp[row][jp] with jp = tid*4+g contiguous (float4 per r) -> the recurrence
// reads ONE float2 (cols 2t, 2t+1) per step per thread.
__global__ __launch_bounds__(256) void xproj_kernel(
        const float* __restrict__ X, const float* __restrict__ wx4,
        const float* __restrict__ bias4, float4* __restrict__ xp) {
    __shared__ __align__(16) float xl[256 * 20];   // [k][row] padded
    int tid = threadIdx.x;
    int R0 = blockIdx.x * 16;
    #pragma unroll
    for (int i = 0; i < 16; ++i)
        xl[tid * 20 + i] = X[(size_t)(R0 + i) * DIM + tid];
    __syncthreads();

    float4 bv = ((const float4*)bias4)[tid];
    float acc[16][4];
    #pragma unroll
    for (int i = 0; i < 16; ++i) {
        acc[i][0] = bv.x; acc[i][1] = bv.y; acc[i][2] = bv.z; acc[i][3] = bv.w;
    }
    const float4* __restrict__ wp = (const float4*)wx4 + tid;
    #pragma unroll 2
    for (int k = 0; k < 256; ++k) {
        float4 w  = wp[k << 8];
        float4 xa = *(const float4*)&xl[k * 20 + 0];
        float4 xb = *(const float4*)&xl[k * 20 + 4];
        float4 xc = *(const float4*)&xl[k * 20 + 8];
        float4 xd = *(const float4*)&xl[k * 20 + 12];
        float xr[16] = {xa.x, xa.y, xa.z, xa.w, xb.x, xb.y, xb.z, xb.w,
                        xc.x, xc.y, xc.z, xc.w, xd.x, xd.y, xd.z, xd.w};
        #pragma unroll
        for (int i = 0; i < 16; ++i) {
            acc[i][0] = fmaf(xr[i], w.x, acc[i][0]);
            acc[i][1] = fmaf(xr[i], w.y, acc[i][1]);
            acc[i][2] = fmaf(xr[i], w.z, acc[i][2]);
            acc[i][3] = fmaf(xr[i], w.w, acc[i][3]);
        }
    }
    #pragma unroll
    for (int i = 0; i < 16; ++i) {
        float4 v;
        v.x = acc[i][0]; v.y = acc[i][1]; v.z = acc[i][2]; v.w = acc[i][3];
        xp[(size_t)(R0 + i) * 256 + tid] = v;
    }
}

// ---------------- phase 2: sequential recurrence, 1 WG per batch element -----
// 512 threads (8 waves, 2/SIMD). Thread t owns cols 2t,2t+1 (jp=4r+g), so the
// LANE PAIR (t even: f,i of row r=t>>1 | t odd: g~,o) holds all 4 gates ->
// exchange via 2 DPP quad_perm ops (VALU, in-wave). c pair-replicated in regs.
// ONE __syncthreads per step (hl double-buffered); out-store post-barrier so
// its ack drains at the NEXT step's barrier; next-step xp prefetched early.
// Weights: k8 0..7 in 128 KB LDS; k8 8..31 in 48 uint4/thread (as baseline).
__global__ __launch_bounds__(512, 2) void lstm_step_kernel(
        const float* __restrict__ xp, const _Float16* __restrict__ whB,
        float* __restrict__ hstate, float* __restrict__ cstate,
        float* __restrict__ out, int t0, int Tc) {
    __shared__ __align__(16) _Float16 wl[8 * 2 * 512 * 8];   // 128 KB: k8 = 0..7
    __shared__ __align__(16) _Float16 hl[2][HID];            // double-buffered h
    int t = threadIdx.x, b = blockIdx.x;

    // stage k8 = 0..7 into LDS (8192 uint4 over 512 threads = 16 each)
    {
        const uint4* src = (const uint4*)whB;
        uint4* dst = (uint4*)wl;
        #pragma unroll
        for (int i = 0; i < 16; ++i)
            dst[i * 512 + t] = src[i * 512 + t];
    }
    // register slab: k8 = 8..31 for cols 2t (slot 0) and 2t+1 (slot 1)
    uint4 wr0[24], wr1[24];
    {
        const uint4* src = (const uint4*)whB;
        #pragma unroll
        for (int i = 0; i < 24; ++i) {
            wr0[i] = src[(size_t)((8 + i) * 2 + 0) * 512 + t];
            wr1[i] = src[(size_t)((8 + i) * 2 + 1) * 512 + t];
        }
    }
    int podd = t & 1;
    float creg = cstate[b * HID + (t >> 1)];       // pair-replicated
    if (t < HID) hl[0][t] = (_Float16)hstate[b * HID + t];
    // branchless gate-A activation: even: sigm(x); odd: tanh(x)=2*sigm(2x)-1
    float sm = podd ? 2.0f : 1.0f;
    float aa = podd ? 2.0f : 1.0f;
    float bbc = podd ? -1.0f : 0.0f;
    __syncthreads();

    const float2* __restrict__ xpf2 = (const float2*)xp;
    float2 xa2 = xpf2[((size_t)0 * BATCH + b) * 512 + t];
    int cur = 0;
    for (int tt = 0; tt < Tc; ++tt) {
        // prefetch next step's xp early (hides L2 latency under the dot chain)
        int tn = (tt + 1 < Tc) ? tt + 1 : tt;
        float2 xn2 = xpf2[((size_t)tn * BATCH + b) * 512 + t];

        float s0a = 0.f, s0b = 0.f, s1a = 0.f, s1b = 0.f;
        const _Float16* hb = hl[cur];
        // LDS-slab part: k8 = 0..7
        #pragma unroll
        for (int k8 = 0; k8 < 8; ++k8) {
            U16 h, w0, w1;
            h.u  = *(const uint4*)&hb[k8 * 8];                          // broadcast
            w0.u = *(const uint4*)&wl[((size_t)(k8 * 2 + 0) * 512 + t) * 8];
            w1.u = *(const uint4*)&wl[((size_t)(k8 * 2 + 1) * 512 + t) * 8];
            s0a = __builtin_amdgcn_fdot2(w0.h[0], h.h[0], s0a, false);
            s0b = __builtin_amdgcn_fdot2(w0.h[1], h.h[1], s0b, false);
            s0a = __builtin_amdgcn_fdot2(w0.h[2], h.h[2], s0a, false);
            s0b = __builtin_amdgcn_fdot2(w0.h[3], h.h[3], s0b, false);
            s1a = __builtin_amdgcn_fdot2(w1.h[0], h.h[0], s1a, false);
            s1b = __builtin_amdgcn_fdot2(w1.h[1], h.h[1], s1b, false);
            s1a = __builtin_amdgcn_fdot2(w1.h[2], h.h[2], s1a, false);
            s1b = __builtin_amdgcn_fdot2(w1.h[3], h.h[3], s1b, false);
        }
        // register-slab part: k8 = 8..31
        #pragma unroll
        for (int i = 0; i < 24; ++i) {
            U16 h, w0, w1;
            h.u  = *(const uint4*)&hb[(8 + i) * 8];                     // broadcast
            w0.u = wr0[i];
            w1.u = wr1[i];
            s0a = __builtin_amdgcn_fdot2(w0.h[0], h.h[0], s0a, false);
            s0b = __builtin_amdgcn_fdot2(w0.h[1], h.h[1], s0b, false);
            s0a = __builtin_amdgcn_fdot2(w0.h[2], h.h[2], s0a, false);
            s0b = __builtin_amdgcn_fdot2(w0.h[3], h.h[3], s0b, false);
            s1a = __builtin_amdgcn_fdot2(w1.h[0], h.h[0], s1a, false);
            s1b = __builtin_amdgcn_fdot2(w1.h[1], h.h[1], s1b, false);
            s1a = __builtin_amdgcn_fdot2(w1.h[2], h.h[2], s1a, false);
            s1b = __builtin_amdgcn_fdot2(w1.h[3], h.h[3], s1b, false);
        }
        float a0 = xa2.x + s0a + s0b;      // col 2t   (even: f | odd: g~)
        float a1 = xa2.y + s1a + s1b;      // col 2t+1 (even: i | odd: o)
        float vA = fmaf(aa, sigm_f(sm * a0), bbc);
        float vB = sigm_f(a1);
        float eA = QP_XOR1(vA);            // partner's A value
        float eB = QP_XOR1(vB);            // partner's B value
        float f  = podd ? eA : vA;
        float ii = podd ? eB : vB;
        float gg = podd ? vA : eA;
        float o  = podd ? vB : eB;
        float c  = fmaf(f, creg, ii * gg);
        creg = c;
        float h  = o * tanh_f(c);
        if (!podd) hl[cur ^ 1][t >> 1] = (_Float16)h;
        __syncthreads();
        // coalesced out-store post-barrier (drains at next step's barrier)
        if (t < HID)
            out[((size_t)(t0 + tt) * BATCH + b) * HID + t] = (float)hl[cur ^ 1][t];
        xa2 = xn2;
        cur ^= 1;
    }
    if (t < HID) hstate[b * HID + t] = (float)hl[cur][t];
    if (!podd)   cstate[b * HID + (t >> 1)] = creg;
}

// ---------------- tail: final hx, cx ------------------------------------------
__global__ void tail_kernel(const float* __restrict__ hstate,
                            const float* __restrict__ cstate, float* __restrict__ out) {
    int b = blockIdx.x, r = threadIdx.x;
    size_t base = (size_t)T_SEQ * BATCH * HID;
    out[base + b * HID + r] = hstate[b * HID + r];
    out[base + (size_t)BATCH * HID + b * HID + r] = cstate[b * HID + r];
}

extern "C" void kernel_launch(void* const* d_in, const int* in_sizes, int n_in,
                              void* d_out, int out_size, void* d_ws, size_t ws_size,
                              hipStream_t stream) {
    (void)in_sizes; (void)n_in; (void)out_size;
    const float* X  = (const float*)d_in[0];
    const float* Wf = (const float*)d_in[1];
    const float* bf = (const float*)d_in[2];
    const float* Wi = (const float*)d_in[3];
    const float* bi = (const float*)d_in[4];
    const float* Wg = (const float*)d_in[5];
    const float* bg = (const float*)d_in[6];
    const float* Wo = (const float*)d_in[7];
    const float* bo = (const float*)d_in[8];
    float* out = (float*)d_out;
    char*  ws  = (char*)d_ws;

    const size_t MB = 1 << 20, KB = 1 << 10;
    float*    wx4    = (float*)(ws);                          // 1 MB
    _Float16* whB    = (_Float16*)(ws + MB);                  // 512 KB
    float*    bias4  = (float*)(ws + MB + 512 * KB);          // 4 KB
    float*    hstate = (float*)(ws + MB + 576 * KB);          // 64 KB
    float*    cstate = (float*)(ws + MB + 640 * KB);          // 64 KB
    float4*   xproj  = (float4*)(ws + 2 * MB);

    size_t fixed = 2 * MB;
    int Tc = 1024;
    while (Tc > 16 && fixed + (size_t)Tc * BATCH * NG * 4 > ws_size) Tc >>= 1;

    pack_kernel<<<256, 1024, 0, stream>>>(Wf, bf, Wi, bi, Wg, bg, Wo, bo,
                                          wx4, whB, bias4, hstate, cstate);
    for (int t0 = 0; t0 < T_SEQ; t0 += Tc) {
        xproj_kernel<<<Tc * BATCH / 16, 256, 0, stream>>>(
            X + (size_t)t0 * BATCH * DIM, wx4, bias4, xproj);
        lstm_step_kernel<<<BATCH, 512, 0, stream>>>(
            (const float*)xproj, whB, hstate, cstate, out, t0, Tc);
    }
    tail_kernel<<<BATCH, HID, 0, stream>>>(hstate, cstate, out);
}